// Round 2
// baseline (642.931 us; speedup 1.0000x reference)
//
#include <hip/hip_runtime.h>

#define B_   2
#define N_   32768
#define M_   4096
#define C_   128
#define OUT_ 128
#define IN_  131

// ---------------------------------------------------------------------------
// K0: pack sampled points as (s0,s1,s2,|s|^2) float4, |s|^2 in the reference's
// exact rounding order.
// ---------------------------------------------------------------------------
__global__ __launch_bounds__(256) void pack_kernel(const float* __restrict__ sx,
                                                   float4* __restrict__ packed) {
    const int t = blockIdx.x * 256 + threadIdx.x;   // [0, B_*M_)
    if (t >= B_ * M_) return;
    float s0 = sx[3*t+0], s1 = sx[3*t+1], s2 = sx[3*t+2];
    float ss = __fadd_rn(__fadd_rn(__fmul_rn(s0,s0), __fmul_rn(s1,s1)),
                         __fmul_rn(s2,s2));
    packed[t] = make_float4(s0, s1, s2, ss);
}

// ---------------------------------------------------------------------------
// K1: brute-force 3-NN. The candidate point is WAVE-UNIFORM (loop counter
// index into a read-only packed buffer) -> compiler emits scalar loads
// (s_load) through the scalar cache; no LDS, no vector-memory traffic in the
// hot loop. Inner loop is pure VALU: 8 insts/point.
// d2 = fma(-2,dot,xx) + ss is bitwise-identical to the reference's
// (xx - 2*dot) + ss  (2*dot is exact), so near-tie neighbor ordering matches
// the fp32 np reference exactly; strict '<' keeps the lower index on ties.
// ---------------------------------------------------------------------------
__global__ __launch_bounds__(128) void nn_kernel(const float* __restrict__ x,
                                                 const float4* __restrict__ packed,
                                                 int4* __restrict__ idx_out) {
    const int qi = blockIdx.x * 128 + threadIdx.x;   // [0, 65536)
    const int b  = qi >> 15;                          // N_=32768
    const float4* __restrict__ sp = packed + (size_t)b * M_;

    const float x0 = x[(size_t)qi*3+0];
    const float x1 = x[(size_t)qi*3+1];
    const float x2 = x[(size_t)qi*3+2];
    const float xx = __fadd_rn(__fadd_rn(__fmul_rn(x0,x0), __fmul_rn(x1,x1)),
                               __fmul_rn(x2,x2));

    float b0 = 1e30f, b1v = 1e30f, b2v = 1e30f;
    int   i0 = 0,     i1 = 0,      i2 = 0;

    for (int m0 = 0; m0 < M_; m0 += 8) {
        #pragma unroll
        for (int j = 0; j < 8; ++j) {
            const int m = m0 + j;
            float4 s = sp[m];
            float dot = __fadd_rn(__fadd_rn(__fmul_rn(x0,s.x), __fmul_rn(x1,s.y)),
                                  __fmul_rn(x2,s.z));
            float d2 = __fadd_rn(__fmaf_rn(-2.0f, dot, xx), s.w);
            if (d2 < b2v) {
                if (d2 < b1v) {
                    b2v = b1v; i2 = i1;
                    if (d2 < b0) { b1v = b0; i1 = i0; b0 = d2; i0 = m; }
                    else         { b1v = d2; i1 = m; }
                } else { b2v = d2; i2 = m; }
            }
        }
    }
    idx_out[qi] = make_int4(i0, i1, i2, 0);
}

// ---------------------------------------------------------------------------
// K2: gather 3 neighbor feature rows, average -> I[65536][128].
// 32 lanes (float4 each) per query; gathers are L2-resident (features = 4 MB).
// ---------------------------------------------------------------------------
__global__ __launch_bounds__(256) void interp_kernel(const float* __restrict__ features,
                                                     const int4* __restrict__ idx,
                                                     float4* __restrict__ I) {
    const int t    = blockIdx.x * 256 + threadIdx.x;
    const int qi   = t >> 5;
    const int lane = t & 31;
    const int b    = qi >> 15;
    const int4 v   = idx[qi];
    const float4* fb = (const float4*)features + (size_t)b * M_ * (C_/4);
    float4 f0 = fb[(size_t)v.x * 32 + lane];
    float4 f1 = fb[(size_t)v.y * 32 + lane];
    float4 f2 = fb[(size_t)v.z * 32 + lane];
    float4 r;
    r.x = ((f0.x + f1.x) + f2.x) / 3.0f;
    r.y = ((f0.y + f1.y) + f2.y) / 3.0f;
    r.z = ((f0.z + f1.z) + f2.z) / 3.0f;
    r.w = ((f0.w + f1.w) + f2.w) / 3.0f;
    I[(size_t)qi * 32 + lane] = r;
}

// ---------------------------------------------------------------------------
// K3: A = relu(I @ W1f^T + x @ W1x^T + b1).  128x128 C-tile per block,
// 256 threads, 8x8 micro-tile, K=128 in 8 chunks of 16 staged in LDS.
// The 3 xyz columns of w1 are folded into the epilogue.
// ---------------------------------------------------------------------------
__global__ __launch_bounds__(256) void gemm1_kernel(const float* __restrict__ I,
                                                    const float* __restrict__ x,
                                                    const float* __restrict__ w1,
                                                    const float* __restrict__ b1,
                                                    float* __restrict__ A) {
    __shared__ float sI[16][132];   // [k][row], padded
    __shared__ float sW[16][132];   // [k][out]
    const int row0 = blockIdx.x * 128;
    const int tid  = threadIdx.x;
    const int tr   = tid & 15;      // row group
    const int tc   = tid >> 4;      // col group
    float acc[8][8] = {};

    for (int kc = 0; kc < 8; ++kc) {
        // stage I chunk: 128 rows x 16 k  (512 float4, 2/thread)
        #pragma unroll
        for (int j = 0; j < 2; ++j) {
            int id  = j * 256 + tid;
            int row = id >> 2, kq = id & 3;
            float4 g = ((const float4*)I)[(size_t)(row0 + row) * 32 + kc * 4 + kq];
            sI[kq*4+0][row] = g.x; sI[kq*4+1][row] = g.y;
            sI[kq*4+2][row] = g.z; sI[kq*4+3][row] = g.w;
        }
        // stage W chunk: w1[o][3 + kc*16 + kk]  (scalar, unaligned row of 131)
        {
            int o = tid >> 1, kk0 = (tid & 1) * 8;
            #pragma unroll
            for (int kk = 0; kk < 8; ++kk)
                sW[kk0+kk][o] = w1[(size_t)o * IN_ + 3 + kc*16 + kk0 + kk];
        }
        __syncthreads();
        #pragma unroll
        for (int kk = 0; kk < 16; ++kk) {
            float4 a0 = *(const float4*)&sI[kk][tr*8];
            float4 a1 = *(const float4*)&sI[kk][tr*8+4];
            float4 c0 = *(const float4*)&sW[kk][tc*8];
            float4 c1 = *(const float4*)&sW[kk][tc*8+4];
            float av[8] = {a0.x,a0.y,a0.z,a0.w,a1.x,a1.y,a1.z,a1.w};
            float bv[8] = {c0.x,c0.y,c0.z,c0.w,c1.x,c1.y,c1.z,c1.w};
            #pragma unroll
            for (int i = 0; i < 8; ++i)
                #pragma unroll
                for (int j = 0; j < 8; ++j)
                    acc[i][j] = fmaf(av[i], bv[j], acc[i][j]);
        }
        __syncthreads();
    }

    // epilogue: xyz part + bias + relu, store A
    float wx0[8], wx1[8], wx2[8], bb[8];
    #pragma unroll
    for (int j = 0; j < 8; ++j) {
        int o = tc*8 + j;
        wx0[j] = w1[(size_t)o*IN_+0];
        wx1[j] = w1[(size_t)o*IN_+1];
        wx2[j] = w1[(size_t)o*IN_+2];
        bb[j]  = b1[o];
    }
    #pragma unroll
    for (int i = 0; i < 8; ++i) {
        int r = row0 + tr*8 + i;
        float x0 = x[(size_t)r*3+0], x1 = x[(size_t)r*3+1], x2 = x[(size_t)r*3+2];
        #pragma unroll
        for (int j = 0; j < 8; ++j) {
            float v = acc[i][j] + wx0[j]*x0 + wx1[j]*x1 + wx2[j]*x2 + bb[j];
            acc[i][j] = v > 0.0f ? v : 0.0f;
        }
        float4 o0 = make_float4(acc[i][0], acc[i][1], acc[i][2], acc[i][3]);
        float4 o1 = make_float4(acc[i][4], acc[i][5], acc[i][6], acc[i][7]);
        ((float4*)A)[(size_t)r * 32 + tc*2 + 0] = o0;
        ((float4*)A)[(size_t)r * 32 + tc*2 + 1] = o1;
    }
}

// ---------------------------------------------------------------------------
// K4: Out[b][o][n] = A @ W2^T + b2, stored transposed. Row-blocked micro-tile
// makes each (o, 8 consecutive n) store a pair of float4s.
// ---------------------------------------------------------------------------
__global__ __launch_bounds__(256) void gemm2_kernel(const float* __restrict__ A,
                                                    const float* __restrict__ w2,
                                                    const float* __restrict__ b2,
                                                    float* __restrict__ out) {
    __shared__ float sA[16][132];
    __shared__ float sW[16][132];
    const int row0 = blockIdx.x * 128;
    const int tid  = threadIdx.x;
    const int tr   = tid & 15;
    const int tc   = tid >> 4;
    float acc[8][8] = {};

    for (int kc = 0; kc < 8; ++kc) {
        #pragma unroll
        for (int j = 0; j < 2; ++j) {
            int id  = j * 256 + tid;
            int row = id >> 2, kq = id & 3;
            float4 g = ((const float4*)A)[(size_t)(row0 + row) * 32 + kc * 4 + kq];
            sA[kq*4+0][row] = g.x; sA[kq*4+1][row] = g.y;
            sA[kq*4+2][row] = g.z; sA[kq*4+3][row] = g.w;
            float4 h = ((const float4*)w2)[(size_t)row * 32 + kc * 4 + kq];
            sW[kq*4+0][row] = h.x; sW[kq*4+1][row] = h.y;
            sW[kq*4+2][row] = h.z; sW[kq*4+3][row] = h.w;
        }
        __syncthreads();
        #pragma unroll
        for (int kk = 0; kk < 16; ++kk) {
            float4 a0 = *(const float4*)&sA[kk][tr*8];
            float4 a1 = *(const float4*)&sA[kk][tr*8+4];
            float4 c0 = *(const float4*)&sW[kk][tc*8];
            float4 c1 = *(const float4*)&sW[kk][tc*8+4];
            float av[8] = {a0.x,a0.y,a0.z,a0.w,a1.x,a1.y,a1.z,a1.w};
            float bv[8] = {c0.x,c0.y,c0.z,c0.w,c1.x,c1.y,c1.z,c1.w};
            #pragma unroll
            for (int i = 0; i < 8; ++i)
                #pragma unroll
                for (int j = 0; j < 8; ++j)
                    acc[i][j] = fmaf(av[i], bv[j], acc[i][j]);
        }
        __syncthreads();
    }

    const int b  = row0 >> 15;
    const int n0 = (row0 & (N_-1)) + tr*8;
    #pragma unroll
    for (int j = 0; j < 8; ++j) {
        int o = tc*8 + j;
        float bias = b2[o];
        float4 o0 = make_float4(acc[0][j]+bias, acc[1][j]+bias,
                                acc[2][j]+bias, acc[3][j]+bias);
        float4 o1 = make_float4(acc[4][j]+bias, acc[5][j]+bias,
                                acc[6][j]+bias, acc[7][j]+bias);
        float* dst = out + (((size_t)(b*OUT_ + o)) << 15) + n0;
        *(float4*)dst       = o0;
        *(float4*)(dst + 4) = o1;
    }
}

extern "C" void kernel_launch(void* const* d_in, const int* in_sizes, int n_in,
                              void* d_out, int out_size, void* d_ws, size_t ws_size,
                              hipStream_t stream) {
    const float* x        = (const float*)d_in[0];   // [B,N,3]
    const float* sx       = (const float*)d_in[1];   // [B,M,3]
    const float* features = (const float*)d_in[2];   // [B,M,C]
    const float* w1       = (const float*)d_in[3];   // [128,131]
    const float* b1       = (const float*)d_in[4];   // [128]
    const float* w2       = (const float*)d_in[5];   // [128,128]
    const float* b2       = (const float*)d_in[6];   // [128]
    float* out = (float*)d_out;                      // [B,128,N]

    char* ws = (char*)d_ws;
    // Layout (65 MB total, same footprint as R1):
    //   [0,1MB)        idx
    //   [1MB,33MB)     I
    //   [33MB,65MB)    A   (first 128KB doubles as `packed`, which is dead
    //                       before gemm1 writes A)
    int4*   idxb   = (int4*)ws;
    float*  I      = (float*)(ws + (1u  << 20));
    float*  A      = (float*)(ws + (33u << 20));
    float4* packed = (float4*)(ws + (33u << 20));

    pack_kernel  <<<dim3((B_*M_ + 255)/256), dim3(256), 0, stream>>>(sx, packed);
    nn_kernel    <<<dim3(B_*N_/128), dim3(128), 0, stream>>>(x, packed, idxb);
    interp_kernel<<<dim3(B_*N_*32/256), dim3(256), 0, stream>>>(features, idxb, (float4*)I);
    gemm1_kernel <<<dim3(B_*N_/128), dim3(256), 0, stream>>>(I, x, w1, b1, A);
    gemm2_kernel <<<dim3(B_*N_/128), dim3(256), 0, stream>>>(A, w2, b2, out);
}

// Round 4
// 373.330 us; speedup vs baseline: 1.7222x; 1.7222x over previous
//
#include <hip/hip_runtime.h>

#define B_   2
#define N_   32768
#define M_   4096
#define C_   128
#define OUT_ 128
#define IN_  131

#define NSPLIT 16
#define MCHUNK (M_ / NSPLIT)     // 256 points per split
#define QPT    4                 // queries per thread in nn kernel
#define NQ     (B_ * N_)         // 65536 total queries

// ---------------------------------------------------------------------------
// K0: pack sampled points as (s0,s1,s2,|s|^2) float4, |s|^2 in the reference's
// exact rounding order.
// ---------------------------------------------------------------------------
__global__ __launch_bounds__(256) void pack_kernel(const float* __restrict__ sx,
                                                   float4* __restrict__ packed) {
    const int t = blockIdx.x * 256 + threadIdx.x;   // [0, B_*M_)
    if (t >= B_ * M_) return;
    float s0 = sx[3*t+0], s1 = sx[3*t+1], s2 = sx[3*t+2];
    float ss = __fadd_rn(__fadd_rn(__fmul_rn(s0,s0), __fmul_rn(s1,s1)),
                         __fmul_rn(s2,s2));
    packed[t] = make_float4(s0, s1, s2, ss);
}

// ---------------------------------------------------------------------------
// K1: split brute-force 3-NN. Each block: 1024 consecutive queries x one
// 256-point chunk of M. 256 threads x QPT=4 queries/thread, so one LDS
// point-read feeds 32 VALU insts (LDS pipe ~12cyc vs ~64cyc VALU). 16 splits
// give 1024 blocks -> 4 blocks/CU, 4KB LDS each.
// d2 = fma(-2,dot,xx) + ss is bitwise-identical to (xx - 2*dot) + ss
// (2*dot exact), matching the fp32 reference's rounding; strict '<' keeps
// the earlier (lower-m) candidate on ties, matching lax.top_k stability.
// Emits per-(query,split) partial top-3 (d2, m).
// ---------------------------------------------------------------------------
__global__ __launch_bounds__(256) void nn_split_kernel(const float* __restrict__ x,
                                                       const float4* __restrict__ packed,
                                                       float4* __restrict__ part_d,
                                                       int4* __restrict__ part_i) {
    __shared__ float4 spts[MCHUNK];   // 4 KB
    const int split = blockIdx.x & (NSPLIT - 1);
    const int qb    = blockIdx.x >> 4;
    const int q0    = qb * 1024;
    const int b     = q0 >> 15;                     // N_=32768
    const int t     = threadIdx.x;

    // stage this split's points
    spts[t] = packed[(size_t)b * M_ + split * MCHUNK + t];
    __syncthreads();

    float x0[QPT], x1[QPT], x2[QPT], xx[QPT];
    float bd0[QPT], bd1[QPT], bd2[QPT];
    int   bi0[QPT], bi1[QPT], bi2[QPT];
    #pragma unroll
    for (int qq = 0; qq < QPT; ++qq) {
        const int qi = q0 + qq * 256 + t;
        x0[qq] = x[(size_t)qi*3+0];
        x1[qq] = x[(size_t)qi*3+1];
        x2[qq] = x[(size_t)qi*3+2];
        xx[qq] = __fadd_rn(__fadd_rn(__fmul_rn(x0[qq],x0[qq]),
                                     __fmul_rn(x1[qq],x1[qq])),
                           __fmul_rn(x2[qq],x2[qq]));
        bd0[qq] = 1e30f; bd1[qq] = 1e30f; bd2[qq] = 1e30f;
        bi0[qq] = 0;     bi1[qq] = 0;     bi2[qq] = 0;
    }

    const int m_base = split * MCHUNK;
    #pragma unroll 4
    for (int j = 0; j < MCHUNK; ++j) {
        float4 s = spts[j];
        const int m = m_base + j;
        #pragma unroll
        for (int qq = 0; qq < QPT; ++qq) {
            float dot = __fadd_rn(__fadd_rn(__fmul_rn(x0[qq],s.x),
                                            __fmul_rn(x1[qq],s.y)),
                                  __fmul_rn(x2[qq],s.z));
            float d2 = __fadd_rn(__fmaf_rn(-2.0f, dot, xx[qq]), s.w);
            if (d2 < bd2[qq]) {
                if (d2 < bd1[qq]) {
                    bd2[qq] = bd1[qq]; bi2[qq] = bi1[qq];
                    if (d2 < bd0[qq]) { bd1[qq] = bd0[qq]; bi1[qq] = bi0[qq];
                                        bd0[qq] = d2;      bi0[qq] = m; }
                    else              { bd1[qq] = d2;      bi1[qq] = m; }
                } else { bd2[qq] = d2; bi2[qq] = m; }
            }
        }
    }

    #pragma unroll
    for (int qq = 0; qq < QPT; ++qq) {
        const int qi = q0 + qq * 256 + t;
        part_d[(size_t)split * NQ + qi] = make_float4(bd0[qq], bd1[qq], bd2[qq], 0.f);
        part_i[(size_t)split * NQ + qi] = make_int4 (bi0[qq], bi1[qq], bi2[qq], 0);
    }
}

// ---------------------------------------------------------------------------
// K1b: merge 16 partial top-3s per query. Candidates processed in ascending-m
// order (split asc, rank asc) with strict '<' -> first-wins tie handling,
// identical selection to a single pass over all 4096 points.
// ---------------------------------------------------------------------------
__device__ __forceinline__ void ins3(float d, int m, float& b0, float& b1, float& b2,
                                     int& i0, int& i1, int& i2) {
    if (d < b2) {
        if (d < b1) {
            b2 = b1; i2 = i1;
            if (d < b0) { b1 = b0; i1 = i0; b0 = d; i0 = m; }
            else        { b1 = d;  i1 = m; }
        } else { b2 = d; i2 = m; }
    }
}

__global__ __launch_bounds__(256) void merge_kernel(const float4* __restrict__ part_d,
                                                    const int4* __restrict__ part_i,
                                                    int4* __restrict__ idx_out) {
    const int q = blockIdx.x * 256 + threadIdx.x;
    float b0 = 1e30f, b1 = 1e30f, b2 = 1e30f;
    int   i0 = 0,     i1 = 0,     i2 = 0;
    #pragma unroll
    for (int s = 0; s < NSPLIT; ++s) {
        float4 d = part_d[(size_t)s * NQ + q];
        int4   i = part_i[(size_t)s * NQ + q];
        ins3(d.x, i.x, b0, b1, b2, i0, i1, i2);
        ins3(d.y, i.y, b0, b1, b2, i0, i1, i2);
        ins3(d.z, i.z, b0, b1, b2, i0, i1, i2);
    }
    idx_out[q] = make_int4(i0, i1, i2, 0);
}

// ---------------------------------------------------------------------------
// K2: gather 3 neighbor feature rows, average -> I[65536][128].
// ---------------------------------------------------------------------------
__global__ __launch_bounds__(256) void interp_kernel(const float* __restrict__ features,
                                                     const int4* __restrict__ idx,
                                                     float4* __restrict__ I) {
    const int t    = blockIdx.x * 256 + threadIdx.x;
    const int qi   = t >> 5;
    const int lane = t & 31;
    const int b    = qi >> 15;
    const int4 v   = idx[qi];
    const float4* fb = (const float4*)features + (size_t)b * M_ * (C_/4);
    float4 f0 = fb[(size_t)v.x * 32 + lane];
    float4 f1 = fb[(size_t)v.y * 32 + lane];
    float4 f2 = fb[(size_t)v.z * 32 + lane];
    float4 r;
    r.x = ((f0.x + f1.x) + f2.x) / 3.0f;
    r.y = ((f0.y + f1.y) + f2.y) / 3.0f;
    r.z = ((f0.z + f1.z) + f2.z) / 3.0f;
    r.w = ((f0.w + f1.w) + f2.w) / 3.0f;
    I[(size_t)qi * 32 + lane] = r;
}

// ---------------------------------------------------------------------------
// K3: A = relu(I @ W1f^T + x @ W1x^T + b1). 128x128 tile, 8x8 micro-tile.
// ---------------------------------------------------------------------------
__global__ __launch_bounds__(256) void gemm1_kernel(const float* __restrict__ I,
                                                    const float* __restrict__ x,
                                                    const float* __restrict__ w1,
                                                    const float* __restrict__ b1,
                                                    float* __restrict__ A) {
    __shared__ float sI[16][132];
    __shared__ float sW[16][132];
    const int row0 = blockIdx.x * 128;
    const int tid  = threadIdx.x;
    const int tr   = tid & 15;
    const int tc   = tid >> 4;
    float acc[8][8] = {};

    for (int kc = 0; kc < 8; ++kc) {
        #pragma unroll
        for (int j = 0; j < 2; ++j) {
            int id  = j * 256 + tid;
            int row = id >> 2, kq = id & 3;
            float4 g = ((const float4*)I)[(size_t)(row0 + row) * 32 + kc * 4 + kq];
            sI[kq*4+0][row] = g.x; sI[kq*4+1][row] = g.y;
            sI[kq*4+2][row] = g.z; sI[kq*4+3][row] = g.w;
        }
        {
            int o = tid >> 1, kk0 = (tid & 1) * 8;
            #pragma unroll
            for (int kk = 0; kk < 8; ++kk)
                sW[kk0+kk][o] = w1[(size_t)o * IN_ + 3 + kc*16 + kk0 + kk];
        }
        __syncthreads();
        #pragma unroll
        for (int kk = 0; kk < 16; ++kk) {
            float4 a0 = *(const float4*)&sI[kk][tr*8];
            float4 a1 = *(const float4*)&sI[kk][tr*8+4];
            float4 c0 = *(const float4*)&sW[kk][tc*8];
            float4 c1 = *(const float4*)&sW[kk][tc*8+4];
            float av[8] = {a0.x,a0.y,a0.z,a0.w,a1.x,a1.y,a1.z,a1.w};
            float bv[8] = {c0.x,c0.y,c0.z,c0.w,c1.x,c1.y,c1.z,c1.w};
            #pragma unroll
            for (int i = 0; i < 8; ++i)
                #pragma unroll
                for (int j = 0; j < 8; ++j)
                    acc[i][j] = fmaf(av[i], bv[j], acc[i][j]);
        }
        __syncthreads();
    }

    float wx0[8], wx1[8], wx2[8], bb[8];
    #pragma unroll
    for (int j = 0; j < 8; ++j) {
        int o = tc*8 + j;
        wx0[j] = w1[(size_t)o*IN_+0];
        wx1[j] = w1[(size_t)o*IN_+1];
        wx2[j] = w1[(size_t)o*IN_+2];
        bb[j]  = b1[o];
    }
    #pragma unroll
    for (int i = 0; i < 8; ++i) {
        int r = row0 + tr*8 + i;
        float x0 = x[(size_t)r*3+0], x1 = x[(size_t)r*3+1], x2 = x[(size_t)r*3+2];
        #pragma unroll
        for (int j = 0; j < 8; ++j) {
            float v = acc[i][j] + wx0[j]*x0 + wx1[j]*x1 + wx2[j]*x2 + bb[j];
            acc[i][j] = v > 0.0f ? v : 0.0f;
        }
        float4 o0 = make_float4(acc[i][0], acc[i][1], acc[i][2], acc[i][3]);
        float4 o1 = make_float4(acc[i][4], acc[i][5], acc[i][6], acc[i][7]);
        ((float4*)A)[(size_t)r * 32 + tc*2 + 0] = o0;
        ((float4*)A)[(size_t)r * 32 + tc*2 + 1] = o1;
    }
}

// ---------------------------------------------------------------------------
// K4: Out[b][o][n] = A @ W2^T + b2, stored transposed.
// ---------------------------------------------------------------------------
__global__ __launch_bounds__(256) void gemm2_kernel(const float* __restrict__ A,
                                                    const float* __restrict__ w2,
                                                    const float* __restrict__ b2,
                                                    float* __restrict__ out) {
    __shared__ float sA[16][132];
    __shared__ float sW[16][132];
    const int row0 = blockIdx.x * 128;
    const int tid  = threadIdx.x;
    const int tr   = tid & 15;
    const int tc   = tid >> 4;
    float acc[8][8] = {};

    for (int kc = 0; kc < 8; ++kc) {
        #pragma unroll
        for (int j = 0; j < 2; ++j) {
            int id  = j * 256 + tid;
            int row = id >> 2, kq = id & 3;
            float4 g = ((const float4*)A)[(size_t)(row0 + row) * 32 + kc * 4 + kq];
            sA[kq*4+0][row] = g.x; sA[kq*4+1][row] = g.y;
            sA[kq*4+2][row] = g.z; sA[kq*4+3][row] = g.w;
            float4 h = ((const float4*)w2)[(size_t)row * 32 + kc * 4 + kq];
            sW[kq*4+0][row] = h.x; sW[kq*4+1][row] = h.y;
            sW[kq*4+2][row] = h.z; sW[kq*4+3][row] = h.w;
        }
        __syncthreads();
        #pragma unroll
        for (int kk = 0; kk < 16; ++kk) {
            float4 a0 = *(const float4*)&sA[kk][tr*8];
            float4 a1 = *(const float4*)&sA[kk][tr*8+4];
            float4 c0 = *(const float4*)&sW[kk][tc*8];
            float4 c1 = *(const float4*)&sW[kk][tc*8+4];
            float av[8] = {a0.x,a0.y,a0.z,a0.w,a1.x,a1.y,a1.z,a1.w};
            float bv[8] = {c0.x,c0.y,c0.z,c0.w,c1.x,c1.y,c1.z,c1.w};
            #pragma unroll
            for (int i = 0; i < 8; ++i)
                #pragma unroll
                for (int j = 0; j < 8; ++j)
                    acc[i][j] = fmaf(av[i], bv[j], acc[i][j]);
        }
        __syncthreads();
    }

    const int b  = row0 >> 15;
    const int n0 = (row0 & (N_-1)) + tr*8;
    #pragma unroll
    for (int j = 0; j < 8; ++j) {
        int o = tc*8 + j;
        float bias = b2[o];
        float4 o0 = make_float4(acc[0][j]+bias, acc[1][j]+bias,
                                acc[2][j]+bias, acc[3][j]+bias);
        float4 o1 = make_float4(acc[4][j]+bias, acc[5][j]+bias,
                                acc[6][j]+bias, acc[7][j]+bias);
        float* dst = out + (((size_t)(b*OUT_ + o)) << 15) + n0;
        *(float4*)dst       = o0;
        *(float4*)(dst + 4) = o1;
    }
}

extern "C" void kernel_launch(void* const* d_in, const int* in_sizes, int n_in,
                              void* d_out, int out_size, void* d_ws, size_t ws_size,
                              hipStream_t stream) {
    const float* x        = (const float*)d_in[0];   // [B,N,3]
    const float* sx       = (const float*)d_in[1];   // [B,M,3]
    const float* features = (const float*)d_in[2];   // [B,M,C]
    const float* w1       = (const float*)d_in[3];   // [128,131]
    const float* b1       = (const float*)d_in[4];   // [128]
    const float* w2       = (const float*)d_in[5];   // [128,128]
    const float* b2       = (const float*)d_in[6];   // [128]
    float* out = (float*)d_out;                      // [B,128,N]

    char* ws = (char*)d_ws;
    // Layout (65 MB total):
    //   [0,1MB)     idx              (written by merge)
    //   [1,33MB)    I                (packed aliases I base; dead before interp)
    //   [33,65MB)   A                (part_d/part_i alias A; dead before gemm1)
    int4*   idxb   = (int4*)ws;
    float*  I      = (float*)(ws + (1u  << 20));
    float4* packed = (float4*)(ws + (1u  << 20));
    float*  A      = (float*)(ws + (33u << 20));
    float4* part_d = (float4*)(ws + (33u << 20));            // 16 MB
    int4*   part_i = (int4*) (ws + (33u << 20) + (16u<<20)); // 16 MB

    pack_kernel    <<<dim3((B_*M_ + 255)/256), dim3(256), 0, stream>>>(sx, packed);
    nn_split_kernel<<<dim3((NQ/1024) * NSPLIT), dim3(256), 0, stream>>>(x, packed, part_d, part_i);
    merge_kernel   <<<dim3(NQ/256), dim3(256), 0, stream>>>(part_d, part_i, idxb);
    interp_kernel  <<<dim3(NQ*32/256), dim3(256), 0, stream>>>(features, idxb, (float4*)I);
    gemm1_kernel   <<<dim3(NQ/128), dim3(256), 0, stream>>>(I, x, w1, b1, A);
    gemm2_kernel   <<<dim3(NQ/128), dim3(256), 0, stream>>>(A, w2, b2, out);
}

// Round 6
// 314.292 us; speedup vs baseline: 2.0456x; 1.1878x over previous
//
#include <hip/hip_runtime.h>

#define B_   2
#define N_   32768
#define M_   4096
#define C_   128
#define OUT_ 128
#define IN_  131

#define NSPLIT 16
#define MCHUNK (M_ / NSPLIT)     // 256 points per split
#define QPT    4                 // queries per thread in nn kernel
#define NQ     (B_ * N_)         // 65536 total queries

// ---------------------------------------------------------------------------
// K0: pack sampled points as (s0,s1,s2,|s|^2) float4, |s|^2 in the reference's
// exact rounding order.
// ---------------------------------------------------------------------------
__global__ __launch_bounds__(256) void pack_kernel(const float* __restrict__ sx,
                                                   float4* __restrict__ packed) {
    const int t = blockIdx.x * 256 + threadIdx.x;   // [0, B_*M_)
    if (t >= B_ * M_) return;
    float s0 = sx[3*t+0], s1 = sx[3*t+1], s2 = sx[3*t+2];
    float ss = __fadd_rn(__fadd_rn(__fmul_rn(s0,s0), __fmul_rn(s1,s1)),
                         __fmul_rn(s2,s2));
    packed[t] = make_float4(s0, s1, s2, ss);
}

// ---------------------------------------------------------------------------
// K1: split brute-force 3-NN, BRANCHLESS top-3 update (uniform 18 insts/pair):
//   distances: k0'=min(k0,d2); k1'=med3(d2,k0,k1); k2'=med3(d2,k1,k2)
//   indices:   3 cmp (strict '<') + 5 cndmask; candidate m is wave-uniform.
// Strict '<' means an equal-distance candidate ranks AFTER the incumbent ->
// first-wins = lower-m, matching lax.top_k stability. d2 formula is bitwise
// identical to the reference's (xx - 2*dot) + ss.
// R4 lesson: divergent insertion-sort cost ~60 insts/pair wave-wide because
// with 64 lanes x QPT=4 some lane almost always updates; branchless makes the
// cost flat and immune to the 16x restart inflation from M-splitting.
// ---------------------------------------------------------------------------
__global__ __launch_bounds__(256) void nn_split_kernel(const float* __restrict__ x,
                                                       const float4* __restrict__ packed,
                                                       float4* __restrict__ part_d,
                                                       int4* __restrict__ part_i) {
    __shared__ float4 spts[MCHUNK];   // 4 KB
    const int split = blockIdx.x & (NSPLIT - 1);
    const int qb    = blockIdx.x >> 4;
    const int q0    = qb * 1024;
    const int b     = q0 >> 15;                     // N_=32768
    const int t     = threadIdx.x;

    spts[t] = packed[(size_t)b * M_ + split * MCHUNK + t];
    __syncthreads();

    float x0[QPT], x1[QPT], x2[QPT], xx[QPT];
    float bd0[QPT], bd1[QPT], bd2[QPT];
    int   bi0[QPT], bi1[QPT], bi2[QPT];
    #pragma unroll
    for (int qq = 0; qq < QPT; ++qq) {
        const int qi = q0 + qq * 256 + t;
        x0[qq] = x[(size_t)qi*3+0];
        x1[qq] = x[(size_t)qi*3+1];
        x2[qq] = x[(size_t)qi*3+2];
        xx[qq] = __fadd_rn(__fadd_rn(__fmul_rn(x0[qq],x0[qq]),
                                     __fmul_rn(x1[qq],x1[qq])),
                           __fmul_rn(x2[qq],x2[qq]));
        bd0[qq] = 1e30f; bd1[qq] = 1e30f; bd2[qq] = 1e30f;
        bi0[qq] = 0;     bi1[qq] = 0;     bi2[qq] = 0;
    }

    const int m_base = split * MCHUNK;
    #pragma unroll 4
    for (int j = 0; j < MCHUNK; ++j) {
        float4 s = spts[j];
        const int m = m_base + j;
        #pragma unroll
        for (int qq = 0; qq < QPT; ++qq) {
            float dot = __fadd_rn(__fadd_rn(__fmul_rn(x0[qq],s.x),
                                            __fmul_rn(x1[qq],s.y)),
                                  __fmul_rn(x2[qq],s.z));
            float d2 = __fadd_rn(__fmaf_rn(-2.0f, dot, xx[qq]), s.w);
            const float k0 = bd0[qq], k1 = bd1[qq], k2 = bd2[qq];
            const bool c0 = d2 < k0, c1 = d2 < k1, c2 = d2 < k2;
            bi2[qq] = c1 ? bi1[qq] : (c2 ? m : bi2[qq]);
            bi1[qq] = c0 ? bi0[qq] : (c1 ? m : bi1[qq]);
            bi0[qq] = c0 ? m : bi0[qq];
            bd0[qq] = fminf(k0, d2);
            bd1[qq] = __builtin_amdgcn_fmed3f(d2, k0, k1);
            bd2[qq] = __builtin_amdgcn_fmed3f(d2, k1, k2);
        }
    }

    #pragma unroll
    for (int qq = 0; qq < QPT; ++qq) {
        const int qi = q0 + qq * 256 + t;
        part_d[(size_t)split * NQ + qi] = make_float4(bd0[qq], bd1[qq], bd2[qq], 0.f);
        part_i[(size_t)split * NQ + qi] = make_int4 (bi0[qq], bi1[qq], bi2[qq], 0);
    }
}

// ---------------------------------------------------------------------------
// K1b: merge 16 partial top-3s per query. Candidates processed in ascending-m
// order (split asc, rank asc) with strict '<' -> first-wins tie handling,
// identical selection to a single pass over all 4096 points.
// ---------------------------------------------------------------------------
__device__ __forceinline__ void ins3(float d, int m, float& b0, float& b1, float& b2,
                                     int& i0, int& i1, int& i2) {
    if (d < b2) {
        if (d < b1) {
            b2 = b1; i2 = i1;
            if (d < b0) { b1 = b0; i1 = i0; b0 = d; i0 = m; }
            else        { b1 = d;  i1 = m; }
        } else { b2 = d; i2 = m; }
    }
}

__global__ __launch_bounds__(256) void merge_kernel(const float4* __restrict__ part_d,
                                                    const int4* __restrict__ part_i,
                                                    int4* __restrict__ idx_out) {
    const int q = blockIdx.x * 256 + threadIdx.x;
    float b0 = 1e30f, b1 = 1e30f, b2 = 1e30f;
    int   i0 = 0,     i1 = 0,     i2 = 0;
    #pragma unroll
    for (int s = 0; s < NSPLIT; ++s) {
        float4 d = part_d[(size_t)s * NQ + q];
        int4   i = part_i[(size_t)s * NQ + q];
        ins3(d.x, i.x, b0, b1, b2, i0, i1, i2);
        ins3(d.y, i.y, b0, b1, b2, i0, i1, i2);
        ins3(d.z, i.z, b0, b1, b2, i0, i1, i2);
    }
    idx_out[q] = make_int4(i0, i1, i2, 0);
}

// ---------------------------------------------------------------------------
// K2: gather 3 neighbor feature rows, average -> I[65536][128].
// ---------------------------------------------------------------------------
__global__ __launch_bounds__(256) void interp_kernel(const float* __restrict__ features,
                                                     const int4* __restrict__ idx,
                                                     float4* __restrict__ I) {
    const int t    = blockIdx.x * 256 + threadIdx.x;
    const int qi   = t >> 5;
    const int lane = t & 31;
    const int b    = qi >> 15;
    const int4 v   = idx[qi];
    const float4* fb = (const float4*)features + (size_t)b * M_ * (C_/4);
    float4 f0 = fb[(size_t)v.x * 32 + lane];
    float4 f1 = fb[(size_t)v.y * 32 + lane];
    float4 f2 = fb[(size_t)v.z * 32 + lane];
    float4 r;
    r.x = ((f0.x + f1.x) + f2.x) / 3.0f;
    r.y = ((f0.y + f1.y) + f2.y) / 3.0f;
    r.z = ((f0.z + f1.z) + f2.z) / 3.0f;
    r.w = ((f0.w + f1.w) + f2.w) / 3.0f;
    I[(size_t)qi * 32 + lane] = r;
}

// ---------------------------------------------------------------------------
// K3: A = relu(I @ W1f^T + x @ W1x^T + b1). 128x128 tile, 8x8 micro-tile.
// ---------------------------------------------------------------------------
__global__ __launch_bounds__(256) void gemm1_kernel(const float* __restrict__ I,
                                                    const float* __restrict__ x,
                                                    const float* __restrict__ w1,
                                                    const float* __restrict__ b1,
                                                    float* __restrict__ A) {
    __shared__ float sI[16][132];
    __shared__ float sW[16][132];
    const int row0 = blockIdx.x * 128;
    const int tid  = threadIdx.x;
    const int tr   = tid & 15;
    const int tc   = tid >> 4;
    float acc[8][8] = {};

    for (int kc = 0; kc < 8; ++kc) {
        #pragma unroll
        for (int j = 0; j < 2; ++j) {
            int id  = j * 256 + tid;
            int row = id >> 2, kq = id & 3;
            float4 g = ((const float4*)I)[(size_t)(row0 + row) * 32 + kc * 4 + kq];
            sI[kq*4+0][row] = g.x; sI[kq*4+1][row] = g.y;
            sI[kq*4+2][row] = g.z; sI[kq*4+3][row] = g.w;
        }
        {
            int o = tid >> 1, kk0 = (tid & 1) * 8;
            #pragma unroll
            for (int kk = 0; kk < 8; ++kk)
                sW[kk0+kk][o] = w1[(size_t)o * IN_ + 3 + kc*16 + kk0 + kk];
        }
        __syncthreads();
        #pragma unroll
        for (int kk = 0; kk < 16; ++kk) {
            float4 a0 = *(const float4*)&sI[kk][tr*8];
            float4 a1 = *(const float4*)&sI[kk][tr*8+4];
            float4 c0 = *(const float4*)&sW[kk][tc*8];
            float4 c1 = *(const float4*)&sW[kk][tc*8+4];
            float av[8] = {a0.x,a0.y,a0.z,a0.w,a1.x,a1.y,a1.z,a1.w};
            float bv[8] = {c0.x,c0.y,c0.z,c0.w,c1.x,c1.y,c1.z,c1.w};
            #pragma unroll
            for (int i = 0; i < 8; ++i)
                #pragma unroll
                for (int j = 0; j < 8; ++j)
                    acc[i][j] = fmaf(av[i], bv[j], acc[i][j]);
        }
        __syncthreads();
    }

    float wx0[8], wx1[8], wx2[8], bb[8];
    #pragma unroll
    for (int j = 0; j < 8; ++j) {
        int o = tc*8 + j;
        wx0[j] = w1[(size_t)o*IN_+0];
        wx1[j] = w1[(size_t)o*IN_+1];
        wx2[j] = w1[(size_t)o*IN_+2];
        bb[j]  = b1[o];
    }
    #pragma unroll
    for (int i = 0; i < 8; ++i) {
        int r = row0 + tr*8 + i;
        float x0 = x[(size_t)r*3+0], x1 = x[(size_t)r*3+1], x2 = x[(size_t)r*3+2];
        #pragma unroll
        for (int j = 0; j < 8; ++j) {
            float v = acc[i][j] + wx0[j]*x0 + wx1[j]*x1 + wx2[j]*x2 + bb[j];
            acc[i][j] = v > 0.0f ? v : 0.0f;
        }
        float4 o0 = make_float4(acc[i][0], acc[i][1], acc[i][2], acc[i][3]);
        float4 o1 = make_float4(acc[i][4], acc[i][5], acc[i][6], acc[i][7]);
        ((float4*)A)[(size_t)r * 32 + tc*2 + 0] = o0;
        ((float4*)A)[(size_t)r * 32 + tc*2 + 1] = o1;
    }
}

// ---------------------------------------------------------------------------
// K4: Out[b][o][n] = A @ W2^T + b2, stored transposed.
// ---------------------------------------------------------------------------
__global__ __launch_bounds__(256) void gemm2_kernel(const float* __restrict__ A,
                                                    const float* __restrict__ w2,
                                                    const float* __restrict__ b2,
                                                    float* __restrict__ out) {
    __shared__ float sA[16][132];
    __shared__ float sW[16][132];
    const int row0 = blockIdx.x * 128;
    const int tid  = threadIdx.x;
    const int tr   = tid & 15;
    const int tc   = tid >> 4;
    float acc[8][8] = {};

    for (int kc = 0; kc < 8; ++kc) {
        #pragma unroll
        for (int j = 0; j < 2; ++j) {
            int id  = j * 256 + tid;
            int row = id >> 2, kq = id & 3;
            float4 g = ((const float4*)A)[(size_t)(row0 + row) * 32 + kc * 4 + kq];
            sA[kq*4+0][row] = g.x; sA[kq*4+1][row] = g.y;
            sA[kq*4+2][row] = g.z; sA[kq*4+3][row] = g.w;
            float4 h = ((const float4*)w2)[(size_t)row * 32 + kc * 4 + kq];
            sW[kq*4+0][row] = h.x; sW[kq*4+1][row] = h.y;
            sW[kq*4+2][row] = h.z; sW[kq*4+3][row] = h.w;
        }
        __syncthreads();
        #pragma unroll
        for (int kk = 0; kk < 16; ++kk) {
            float4 a0 = *(const float4*)&sA[kk][tr*8];
            float4 a1 = *(const float4*)&sA[kk][tr*8+4];
            float4 c0 = *(const float4*)&sW[kk][tc*8];
            float4 c1 = *(const float4*)&sW[kk][tc*8+4];
            float av[8] = {a0.x,a0.y,a0.z,a0.w,a1.x,a1.y,a1.z,a1.w};
            float bv[8] = {c0.x,c0.y,c0.z,c0.w,c1.x,c1.y,c1.z,c1.w};
            #pragma unroll
            for (int i = 0; i < 8; ++i)
                #pragma unroll
                for (int j = 0; j < 8; ++j)
                    acc[i][j] = fmaf(av[i], bv[j], acc[i][j]);
        }
        __syncthreads();
    }

    const int b  = row0 >> 15;
    const int n0 = (row0 & (N_-1)) + tr*8;
    #pragma unroll
    for (int j = 0; j < 8; ++j) {
        int o = tc*8 + j;
        float bias = b2[o];
        float4 o0 = make_float4(acc[0][j]+bias, acc[1][j]+bias,
                                acc[2][j]+bias, acc[3][j]+bias);
        float4 o1 = make_float4(acc[4][j]+bias, acc[5][j]+bias,
                                acc[6][j]+bias, acc[7][j]+bias);
        float* dst = out + (((size_t)(b*OUT_ + o)) << 15) + n0;
        *(float4*)dst       = o0;
        *(float4*)(dst + 4) = o1;
    }
}

extern "C" void kernel_launch(void* const* d_in, const int* in_sizes, int n_in,
                              void* d_out, int out_size, void* d_ws, size_t ws_size,
                              hipStream_t stream) {
    const float* x        = (const float*)d_in[0];   // [B,N,3]
    const float* sx       = (const float*)d_in[1];   // [B,M,3]
    const float* features = (const float*)d_in[2];   // [B,M,C]
    const float* w1       = (const float*)d_in[3];   // [128,131]
    const float* b1       = (const float*)d_in[4];   // [128]
    const float* w2       = (const float*)d_in[5];   // [128,128]
    const float* b2       = (const float*)d_in[6];   // [128]
    float* out = (float*)d_out;                      // [B,128,N]

    char* ws = (char*)d_ws;
    // Layout (65 MB total):
    //   [0,1MB)     idx              (written by merge)
    //   [1,33MB)    I                (packed aliases I base; dead before interp)
    //   [33,65MB)   A                (part_d/part_i alias A; dead before gemm1)
    int4*   idxb   = (int4*)ws;
    float*  I      = (float*)(ws + (1u  << 20));
    float4* packed = (float4*)(ws + (1u  << 20));
    float*  A      = (float*)(ws + (33u << 20));
    float4* part_d = (float4*)(ws + (33u << 20));            // 16 MB
    int4*   part_i = (int4*) (ws + (33u << 20) + (16u<<20)); // 16 MB

    pack_kernel    <<<dim3((B_*M_ + 255)/256), dim3(256), 0, stream>>>(sx, packed);
    nn_split_kernel<<<dim3((NQ/1024) * NSPLIT), dim3(256), 0, stream>>>(x, packed, part_d, part_i);
    merge_kernel   <<<dim3(NQ/256), dim3(256), 0, stream>>>(part_d, part_i, idxb);
    interp_kernel  <<<dim3(NQ*32/256), dim3(256), 0, stream>>>(features, idxb, (float4*)I);
    gemm1_kernel   <<<dim3(NQ/128), dim3(256), 0, stream>>>(I, x, w1, b1, A);
    gemm2_kernel   <<<dim3(NQ/128), dim3(256), 0, stream>>>(A, w2, b2, out);
}